// Round 14
// baseline (3084.727 us; speedup 1.0000x reference)
//
#include <hip/hip_runtime.h>

#define Hh 64
#define Tt 2048
#define Bb 256
#define NL 3

typedef _Float16 h2 __attribute__((ext_vector_type(2)));

#define FDOT2(a,b,c) __builtin_amdgcn_fdot2((a),(b),(c),false)

__device__ __forceinline__ float fast_sigmoid(float x){ return 1.0f/(1.0f+__expf(-x)); }
__device__ __forceinline__ float fast_tanh(float x){ float e=__expf(2.0f*x); return 1.0f-2.0f/(e+1.0f); }

// Butterfly sum over 8-lane groups with DPP (pure VALU, no LDS, and every lane
// gets a bitwise-identical sum: pair trees are symmetric + fp add commutes).
template<int CTRL>
__device__ __forceinline__ float dpp_add(float v){
    int s = __builtin_amdgcn_update_dpp(0, __float_as_int(v), CTRL, 0xF, 0xF, true);
    return v + __int_as_float(s);
}
__device__ __forceinline__ float oct_sum(float v){
    v = dpp_add<0xB1>(v);    // quad_perm [1,0,3,2] : xor 1
    v = dpp_add<0x4E>(v);    // quad_perm [2,3,0,1] : xor 2
    v = dpp_add<0x141>(v);   // row_half_mirror     : xor 7 (pairs the quads)
    return v;
}

__global__ void conv_w(const float* __restrict__ src, _Float16* __restrict__ dst, int n){
    int i = blockIdx.x*256 + threadIdx.x;
    if (i < n) dst[i] = (_Float16)src[i];
}

__global__ __launch_bounds__(256)
void prep_x(const float* __restrict__ x, _Float16* __restrict__ xh){
    __shared__ float tile[64][65];
    const int b = blockIdx.x, tc = blockIdx.y;
    const int tt = threadIdx.x & 63, hq = threadIdx.x >> 6;
    const long xb = (long)b * Hh * Tt;
#pragma unroll
    for (int k=0;k<16;++k){ int h = hq*16+k; tile[h][tt] = x[xb + (long)h*Tt + tc*64 + tt]; }
    __syncthreads();
    _Float16* dst = xh + ((long)b*Tt + tc*64 + tt)*Hh + hq*16;
#pragma unroll
    for (int k=0;k<16;++k) dst[k] = (_Float16)tile[hq*16+k][tt];
}

// Layer-sequential GRU scan. One block per batch element, 512 thr = 8 waves.
// Lane (j = tid>>3, o = tid&7): unit j, k-octant o. Per lane: 6 weight octs
// (ih r/z/n + hh r/z/n) = 24 f16-packed dwords + ~29 working ~= 53 VGPRs --
// UNDER the backend's observed 64-68 budget (R3-R13: any demand above it gets
// rematerialized/spilled and re-streamed from L2 at ~78B/cyc = whole runtime).
// x-side GEMM fused; x bulk-staged to LDS every 16 steps (per-step global
// prefetch stalls at the compiler's vmcnt(0)-before-barrier drain). DPP
// butterfly -> all gates in-lane -> ONE barrier per step.
template<int LAST>
__global__ __launch_bounds__(512)
void gru_scan(_Float16* __restrict__ xh, float* __restrict__ out,
              const _Float16* __restrict__ wih16, const _Float16* __restrict__ whh16,
              const float* __restrict__ bih, const float* __restrict__ bhh, int l)
{
    const int b = blockIdx.x, tid = threadIdx.x;
    const int j = tid >> 3;   // unit 0..63
    const int o = tid & 7;    // k-octant 0..7

    const _Float16* WI = wih16 + (long)l*192*64;
    const _Float16* WH = whh16 + (long)l*192*64;
    const h2* pir = (const h2*)(WI + (      j)*64 + o*8);
    const h2* piz = (const h2*)(WI + ( 64 + j)*64 + o*8);
    const h2* pin = (const h2*)(WI + (128 + j)*64 + o*8);
    const h2* phr = (const h2*)(WH + (      j)*64 + o*8);
    const h2* phz = (const h2*)(WH + ( 64 + j)*64 + o*8);
    const h2* phn = (const h2*)(WH + (128 + j)*64 + o*8);
    h2 Ur0=pir[0],Ur1=pir[1],Ur2=pir[2],Ur3=pir[3];
    h2 Uz0=piz[0],Uz1=piz[1],Uz2=piz[2],Uz3=piz[3];
    h2 Un0=pin[0],Un1=pin[1],Un2=pin[2],Un3=pin[3];
    h2 Vr0=phr[0],Vr1=phr[1],Vr2=phr[2],Vr3=phr[3];
    h2 Vz0=phz[0],Vz1=phz[1],Vz2=phz[2],Vz3=phz[3];
    h2 Vn0=phn[0],Vn1=phn[1],Vn2=phn[2],Vn3=phn[3];

    const float br  = bih[l*192 +       j] + bhh[l*192 +       j];
    const float bz  = bih[l*192 +  64 + j] + bhh[l*192 +  64 + j];
    const float bnx = bih[l*192 + 128 + j];
    const float bnh = bhh[l*192 + 128 + j];

    __shared__ __align__(16) _Float16 hbuf[2][Hh];          // h double-buffer
    __shared__ __align__(16) _Float16 xstage[2][16][Hh];    // input stage, 2x2KB
    __shared__ __align__(16) _Float16 obuf16[2][16][Hh];    // out stage (LAST=0)
    __shared__ __align__(16) float    obuf32[2][Hh][17];    // out stage (LAST=1), +1 pad

    _Float16* xrow = xh + (long)b * Tt * Hh;   // this block's [T][64] slice
    float*    orow = out + (long)b * Hh * Tt;  // [64][T] (LAST=1)

    if (tid < Hh) hbuf[0][tid] = (_Float16)0.0f;
    if (tid < 128) ((uint4*)&xstage[0][0][0])[tid] = ((const uint4*)xrow)[tid];  // rows 0..15
    __syncthreads();

    float hprev = 0.0f;
    const uint4* ssrc = (const uint4*)xrow + 128 + tid;   // next stage src (rows 16..)
    uint4*       fdst = (uint4*)xrow + tid;               // flush dst (rows 0..)

#pragma unroll 1
    for (int t = 0; t < Tt; ++t) {
        const int tm = t & 15, xb = (t >> 4) & 1;
        if (tm == 0) {
            if (tid < 128) {
                if (t + 16 < Tt) {                 // stage rows t+16..t+31
                    ((uint4*)&xstage[xb^1][0][0])[tid] = *ssrc;
                    ssrc += 128;
                }
                if (LAST == 0 && t > 0) {          // flush rows t-16..t-1 (in-place on xh:
                    *fdst = ((const uint4*)&obuf16[xb^1][0][0])[tid];   // writes trail reads by 17+ rows)
                    fdst += 128;
                }
            }
            if (LAST == 1 && t > 0 && tid < 256) {
                const int jr = tid >> 2, tq = tid & 3;
                const float* s = &obuf32[xb^1][jr][tq*4];
                *(float4*)(orow + (long)jr*Tt + (t-16) + tq*4) = make_float4(s[0],s[1],s[2],s[3]);
            }
        }

        union { uint4 u; h2 h[4]; } X, H;
        X.u = *(const uint4*)&xstage[xb][tm][o*8];   // 8 slots x 8 same-addr lanes: conflict-free
        H.u = *(const uint4*)&hbuf[t & 1][o*8];

        float ar=0.f, az=0.f, anx=0.f, anh=0.f;
        ar  = FDOT2(Ur0,X.h[0],ar);  ar  = FDOT2(Ur1,X.h[1],ar);
        ar  = FDOT2(Ur2,X.h[2],ar);  ar  = FDOT2(Ur3,X.h[3],ar);
        ar  = FDOT2(Vr0,H.h[0],ar);  ar  = FDOT2(Vr1,H.h[1],ar);
        ar  = FDOT2(Vr2,H.h[2],ar);  ar  = FDOT2(Vr3,H.h[3],ar);
        az  = FDOT2(Uz0,X.h[0],az);  az  = FDOT2(Uz1,X.h[1],az);
        az  = FDOT2(Uz2,X.h[2],az);  az  = FDOT2(Uz3,X.h[3],az);
        az  = FDOT2(Vz0,H.h[0],az);  az  = FDOT2(Vz1,H.h[1],az);
        az  = FDOT2(Vz2,H.h[2],az);  az  = FDOT2(Vz3,H.h[3],az);
        anx = FDOT2(Un0,X.h[0],anx); anx = FDOT2(Un1,X.h[1],anx);
        anx = FDOT2(Un2,X.h[2],anx); anx = FDOT2(Un3,X.h[3],anx);
        anh = FDOT2(Vn0,H.h[0],anh); anh = FDOT2(Vn1,H.h[1],anh);
        anh = FDOT2(Vn2,H.h[2],anh); anh = FDOT2(Vn3,H.h[3],anh);

        ar = oct_sum(ar); az = oct_sum(az); anx = oct_sum(anx); anh = oct_sum(anh);

        const float r = fast_sigmoid(ar + br);
        const float z = fast_sigmoid(az + bz);
        const float n = fast_tanh(fmaf(r, anh + bnh, anx + bnx));
        const float hnew = fmaf(z, hprev - n, n);     // (1-z)*n + z*h
        hprev = hnew;                                  // replicated in all 8 lanes (bitwise identical)
        if (o == 0) {
            hbuf[(t & 1) ^ 1][j] = (_Float16)hnew;
            if (LAST == 0) obuf16[xb][tm][j] = (_Float16)hnew;
            else           obuf32[xb][j][tm] = hnew;
        }
        __syncthreads();
    }

    // tail flush: rows Tt-16..Tt-1, parity ((Tt-16)>>4)&1 = 1
    if (LAST == 0) {
        if (tid < 128) *fdst = ((const uint4*)&obuf16[1][0][0])[tid];
    } else if (tid < 256) {
        const int jr = tid >> 2, tq = tid & 3;
        const float* s = &obuf32[1][jr][tq*4];
        *(float4*)(orow + (long)jr*Tt + (Tt-16) + tq*4) = make_float4(s[0],s[1],s[2],s[3]);
    }
}

extern "C" void kernel_launch(void* const* d_in, const int* in_sizes, int n_in,
                              void* d_out, int out_size, void* d_ws, size_t ws_size,
                              hipStream_t stream) {
    const float* x   = (const float*)d_in[0];   // [B, H, T]
    const float* Wih = (const float*)d_in[1];   // [3, 192, 64]
    const float* Whh = (const float*)d_in[2];   // [3, 192, 64]
    const float* bih = (const float*)d_in[3];   // [3, 192]
    const float* bhh = (const float*)d_in[4];   // [3, 192]
    float* out = (float*)d_out;                 // [B, H, T]

    // ws: xh [256][2048][64] f16 (67108864 B) | wih16 | whh16
    _Float16* xh    = (_Float16*)d_ws;
    _Float16* wih16 = (_Float16*)((char*)d_ws + 67108864);
    _Float16* whh16 = (_Float16*)((char*)d_ws + 67108864 + 73728);
    const int nW = NL * 192 * 64;  // 36864

    conv_w<<<(nW + 255) / 256, 256, 0, stream>>>(Wih, wih16, nW);
    conv_w<<<(nW + 255) / 256, 256, 0, stream>>>(Whh, whh16, nW);
    prep_x<<<dim3(Bb, Tt / 64), 256, 0, stream>>>(x, xh);
    // Layer-sequential scans; layers 0,1 run in-place on xh (h_l overwrites input rows
    // 17+ rows behind the staged reads); layer 2 writes f32 [B,H,T] output.
    gru_scan<0><<<Bb, 512, 0, stream>>>(xh, out, wih16, whh16, bih, bhh, 0);
    gru_scan<0><<<Bb, 512, 0, stream>>>(xh, out, wih16, whh16, bih, bhh, 1);
    gru_scan<1><<<Bb, 512, 0, stream>>>(xh, out, wih16, whh16, bih, bhh, 2);
}

// Round 15
// 2559.183 us; speedup vs baseline: 1.2054x; 1.2054x over previous
//
#include <hip/hip_runtime.h>

#define Hh 64
#define Tt 2048
#define Bb 256
#define NL 3

typedef _Float16 h2 __attribute__((ext_vector_type(2)));

__device__ __forceinline__ h2 uh2(unsigned u){ union{unsigned u; h2 h;}d; d.u=u; return d.h; }
__device__ __forceinline__ unsigned h2u(h2 h){ union{h2 h; unsigned u;}d; d.h=h; return d.u; }
#define FDOT2(a,b,c) __builtin_amdgcn_fdot2((a),(b),(c),false)

__device__ __forceinline__ float fast_sigmoid(float x){ return 1.0f/(1.0f+__expf(-x)); }
__device__ __forceinline__ float fast_tanh(float x){ float e=__expf(2.0f*x); return 1.0f-2.0f/(e+1.0f); }

#define REPEAT16(M) M(0) M(1) M(2) M(3) M(4) M(5) M(6) M(7) \
                    M(8) M(9) M(10) M(11) M(12) M(13) M(14) M(15)

__global__ void conv_w(const float* __restrict__ src, _Float16* __restrict__ dst, int n){
    int i = blockIdx.x*256 + threadIdx.x;
    if (i < n) dst[i] = (_Float16)src[i];
}

__global__ __launch_bounds__(256)
void prep_x(const float* __restrict__ x, _Float16* __restrict__ xh){
    __shared__ float tile[64][65];
    const int b = blockIdx.x, tc = blockIdx.y;
    const int tt = threadIdx.x & 63, hq = threadIdx.x >> 6;
    const long xb = (long)b * Hh * Tt;
#pragma unroll
    for (int k=0;k<16;++k){ int h = hq*16+k; tile[h][tt] = x[xb + (long)h*Tt + tc*64 + tt]; }
    __syncthreads();
    _Float16* dst = xh + ((long)b*Tt + tc*64 + tt)*Hh + hq*16;
#pragma unroll
    for (int k=0;k<16;++k) dst[k] = (_Float16)tile[hq*16+k][tt];
}

// ---- main: 12 waves/block, 4 per layer, layers pipelined with skew 1 ----
// Wave (l, s, uh); lane (kh, jj). Each lane: 3 half-rows of packed f16 = 48
// dwords, held in AGPRs.
//
// R3-R14 lesson: the backend will NOT keep loop-invariant LOADED data in arch
// VGPRs -- it remats the loads into the loop (R4-R12, R14: VGPR=28 at demand
// 53) or spills (R13 volatile), re-streaming ~147KB/block/phase from L2 =
// the entire runtime. Fix: park the weights in AGPRs. The AGPR def is a
// volatile INLINEASM (non-remat: its load operand is dead after the write);
// volatile asm reads in-loop can't be hoisted/duplicated; AGPR spill is an
// expensive explicit round-trip the RA avoids. 48 AGPR + ~35 VGPR fits 3
// waves/SIMD trivially.
__global__
__attribute__((amdgpu_flat_work_group_size(768, 768)))
__attribute__((amdgpu_waves_per_eu(3, 3)))
void gru_pipe(const _Float16* __restrict__ xh, float* __restrict__ out,
              const _Float16* __restrict__ wih16, const _Float16* __restrict__ whh16,
              const float* __restrict__ bih, const float* __restrict__ bhh)
{
    const int b   = blockIdx.x;
    const int tid = threadIdx.x;
    const int w   = tid >> 6;        // 0..11
    const int l   = w >> 2;          // layer 0..2
    const int s   = (w >> 1) & 1;    // role
    const int uh  = w & 1;           // unit half
    const int ln  = tid & 63;
    const int kh  = ln >> 5;         // k half
    const int jj  = ln & 31;
    const int j   = uh * 32 + jj;    // hidden unit

    const int gA = s ? 64 + j : j;
    const h2* pa = (const h2*)wih16 + ((long)l * 192 + gA) * 32 + kh * 16;
    const h2* pb = (const h2*)whh16 + ((long)l * 192 + gA) * 32 + kh * 16;
    const h2* pc = (const h2*)(s ? wih16 : whh16) + ((long)l * 192 + 128 + j) * 32 + kh * 16;

    // Load once, then park in AGPRs (un-remat'able, un-hoistable defs).
#define DECLA(k) unsigned aA##k, aB##k, aC##k;
    REPEAT16(DECLA)
#undef DECLA
#define TOA(k) { \
    asm volatile("v_accvgpr_write_b32 %0, %1" : "=a"(aA##k) : "v"(h2u(pa[k]))); \
    asm volatile("v_accvgpr_write_b32 %0, %1" : "=a"(aB##k) : "v"(h2u(pb[k]))); \
    asm volatile("v_accvgpr_write_b32 %0, %1" : "=a"(aC##k) : "v"(h2u(pc[k]))); }
    REPEAT16(TOA)
#undef TOA

    // In-loop AGPR -> VGPR read (volatile: pinned inside the loop body).
#define ARD(av) __extension__({ unsigned t_; \
    asm volatile("v_accvgpr_read_b32 %0, %1" : "=v"(t_) : "a"(av)); uh2(t_); })

    float bA = 0.0f, bC = 0.0f;
    if (kh == 0) {
        bA = bih[l*192 + gA] + bhh[l*192 + gA];
        bC = s ? bih[l*192 + 128 + j] : bhh[l*192 + 128 + j];
    }

    __shared__ __align__(16) _Float16 hbuf[NL][2][Hh]; // per-layer h, dbuf by parity
    __shared__ __align__(16) _Float16 xbuf[2][Hh];     // layer-0 input, dbuf
    __shared__ float ubuf[NL][Hh];                     // r*(Whh_n.h + bhn), fp32
    __shared__ float obuf[2][32][33];                  // layer-2 out staging, +1 pad

    const long ib  = (long)b * Hh * Tt;   // [B,H,T] out base
    const long ibh = (long)b * Tt * Hh;   // [B,T,H] xh base

    if (tid < NL * 2 * Hh) ((_Float16*)hbuf)[tid] = (_Float16)0.0f;
    float hprev = 0.0f;
    _Float16 xcur = (_Float16)0.0f, xnext = (_Float16)0.0f;  // wave 8 duty
    if (w == 8) {
        xbuf[0][ln] = xh[ibh + 0 * Hh + ln];
        xcur        = xh[ibh + 1 * Hh + ln];
    }
    __syncthreads();

    const uint4* xsA = (const uint4*)((l == 0) ? xbuf[0] : hbuf[l - 1][0]) + kh * 4;
    const uint4* xsB = (const uint4*)((l == 0) ? xbuf[1] : hbuf[l - 1][1]) + kh * 4;
    const uint4* hsA = (const uint4*)hbuf[l][0] + kh * 4;
    const uint4* hsB = (const uint4*)hbuf[l][1] + kh * 4;

    for (int p = 0; p < Tt + NL - 1; ++p) {
        const int rd = p & 1;
        const int t  = p - l;
        const bool act = (t >= 0) && (t < Tt);

        if (w == 8 && p + 2 < Tt) xnext = xh[ibh + (long)(p + 2) * Hh + ln];

        float accA = bA, accB = 0.0f, accC = bC;
        float zg = 0.0f;
        if (act) {
            const uint4* xs4 = rd ? xsB : xsA;
            const uint4* hs4 = rd ? hsB : hsA;
#define QSTEP(q, k0, k1, k2, k3, S3)  { \
    const uint4 X = xs4[q]; const uint4 Hv = hs4[q]; \
    accA = FDOT2(ARD(aA##k0), uh2(X.x), accA); accB = FDOT2(ARD(aB##k0), uh2(Hv.x), accB); accC = FDOT2(ARD(aC##k0), uh2(S3.x), accC); \
    accA = FDOT2(ARD(aA##k1), uh2(X.y), accA); accB = FDOT2(ARD(aB##k1), uh2(Hv.y), accB); accC = FDOT2(ARD(aC##k1), uh2(S3.y), accC); \
    accA = FDOT2(ARD(aA##k2), uh2(X.z), accA); accB = FDOT2(ARD(aB##k2), uh2(Hv.z), accB); accC = FDOT2(ARD(aC##k2), uh2(S3.z), accC); \
    accA = FDOT2(ARD(aA##k3), uh2(X.w), accA); accB = FDOT2(ARD(aB##k3), uh2(Hv.w), accB); accC = FDOT2(ARD(aC##k3), uh2(S3.w), accC); }
            if (s == 0) {
                QSTEP(0,  0,  1,  2,  3, Hv)
                QSTEP(1,  4,  5,  6,  7, Hv)
                QSTEP(2,  8,  9, 10, 11, Hv)
                QSTEP(3, 12, 13, 14, 15, Hv)
            } else {
                QSTEP(0,  0,  1,  2,  3, X)
                QSTEP(1,  4,  5,  6,  7, X)
                QSTEP(2,  8,  9, 10, 11, X)
                QSTEP(3, 12, 13, 14, 15, X)
            }
#undef QSTEP
            accA += __shfl_xor(accA, 32);
            accB += __shfl_xor(accB, 32);
            accC += __shfl_xor(accC, 32);
            const float g = fast_sigmoid(accA + accB);   // r (s=0) or z (s=1)
            if (s == 0) {
                if (kh == 0) ubuf[l][j] = g * accC;      // u = r*(Whh_n.h + bhn)
            }
            zg = g;
        }
        __syncthreads();   // B1: u visible

        if (act && s == 1) {
            const float n = fast_tanh(accC + ubuf[l][j]);   // accC = Wih_n.x + bxn
            const float hnew = fmaf(zg, hprev - n, n);      // (1-z)*n + z*h
            hprev = hnew;
            if (kh == 0) {
                hbuf[l][rd ^ 1][j] = (_Float16)hnew;
                if (l == NL - 1) obuf[uh][jj][t & 31] = hnew;
            }
        }
        if (w == 8) {
            if (p + 1 < Tt) xbuf[rd ^ 1][ln] = xcur;
            xcur = xnext;
        }
        __syncthreads();   // B2: h/x published for next phase

        if ((w >> 1) == 5 && act && (t & 31) == 31) {
            const float* srow = obuf[uh][jj] + kh * 16;
            float4* dst = (float4*)(out + ib + (long)j * Tt + (t - 31) + kh * 16);
            dst[0] = make_float4(srow[0],  srow[1],  srow[2],  srow[3]);
            dst[1] = make_float4(srow[4],  srow[5],  srow[6],  srow[7]);
            dst[2] = make_float4(srow[8],  srow[9],  srow[10], srow[11]);
            dst[3] = make_float4(srow[12], srow[13], srow[14], srow[15]);
        }
    }
}

extern "C" void kernel_launch(void* const* d_in, const int* in_sizes, int n_in,
                              void* d_out, int out_size, void* d_ws, size_t ws_size,
                              hipStream_t stream) {
    const float* x   = (const float*)d_in[0];   // [B, H, T]
    const float* Wih = (const float*)d_in[1];   // [3, 192, 64]
    const float* Whh = (const float*)d_in[2];   // [3, 192, 64]
    const float* bih = (const float*)d_in[3];   // [3, 192]
    const float* bhh = (const float*)d_in[4];   // [3, 192]
    float* out = (float*)d_out;                 // [B, H, T]

    _Float16* xh    = (_Float16*)d_ws;
    _Float16* wih16 = (_Float16*)((char*)d_ws + 67108864);
    _Float16* whh16 = (_Float16*)((char*)d_ws + 67108864 + 73728);
    const int nW = NL * 192 * 64;  // 36864

    conv_w<<<(nW + 255) / 256, 256, 0, stream>>>(Wih, wih16, nW);
    conv_w<<<(nW + 255) / 256, 256, 0, stream>>>(Whh, whh16, nW);
    prep_x<<<dim3(Bb, Tt / 64), 256, 0, stream>>>(x, xh);
    gru_pipe<<<Bb, 768, 0, stream>>>(xh, out, wih16, whh16, bih, bhh);
}